// Round 7
// baseline (247.971 us; speedup 1.0000x reference)
//
#include <hip/hip_runtime.h>
#include <hip/hip_fp16.h>
#include <stdint.h>

typedef _Float16 f16x8 __attribute__((ext_vector_type(8)));
typedef _Float16 f16x4 __attribute__((ext_vector_type(4)));
typedef float    f32x4 __attribute__((ext_vector_type(4)));

#define MFMA16(a, b, c) __builtin_amdgcn_mfma_f32_16x16x32_f16(a, b, c, 0, 0, 0)

static constexpr int BN   = 8;
static constexpr int CIN  = 512;
static constexpr int NHW  = 4096;
static constexpr int OD   = 256;
static constexpr int KBLK = 32;

// 128B-row XOR swizzle (prep LDS tiles)
#define RSWZ(row, cb) ((((row) << 7)) + ((cb) ^ (((row) & 7) << 4)))

__device__ __forceinline__ f16x8 cvt8(const float4 a, const float4 b) {
    f16x8 r;
    r[0] = (_Float16)a.x; r[1] = (_Float16)a.y; r[2] = (_Float16)a.z; r[3] = (_Float16)a.w;
    r[4] = (_Float16)b.x; r[5] = (_Float16)b.y; r[6] = (_Float16)b.z; r[7] = (_Float16)b.w;
    return r;
}

__device__ __forceinline__ uint32_t pkh2(float x, float y) {
    union { _Float16 h[2]; uint32_t u; } z;
    z.h[0] = (_Float16)x; z.h[1] = (_Float16)y;
    return z.u;
}

// ---------------------------------------------------------------------------
// Convert theta/phi weights to f16 once. wf[sel][o][c], 256x512 each.
// ---------------------------------------------------------------------------
__global__ __launch_bounds__(256)
void wcvt(const float* __restrict__ thw, const float* __restrict__ phw,
          _Float16* __restrict__ wf)
{
    const int i = blockIdx.x * 256 + threadIdx.x;   // 32768 float4 units
    const float4 a = ((const float4*)thw)[i];
    const float4 b = ((const float4*)phw)[i];
    f16x4 ra, rb;
    ra[0] = (_Float16)a.x; ra[1] = (_Float16)a.y; ra[2] = (_Float16)a.z; ra[3] = (_Float16)a.w;
    rb[0] = (_Float16)b.x; rb[1] = (_Float16)b.y; rb[2] = (_Float16)b.z; rb[3] = (_Float16)b.w;
    *(f16x4*)(wf + (size_t)i * 4)          = ra;
    *(f16x4*)(wf + 131072 + (size_t)i * 4) = rb;
}

// ---------------------------------------------------------------------------
// Prep: T[b][n][o] = sum_c x[b][c][n]*w[o][c] + bias[o] -> f16 [n][256].
// grid (64 nt, 16 = b*2+sel), block 256. x read ONCE; full o=256 per block.
// ---------------------------------------------------------------------------
__global__ __launch_bounds__(256)
void prep_gemm(const float* __restrict__ xq, const float* __restrict__ xs,
               const _Float16* __restrict__ wf,
               const float* __restrict__ thb, const float* __restrict__ phb,
               _Float16* __restrict__ Qws, _Float16* __restrict__ Kws)
{
    const int nt = blockIdx.x, z = blockIdx.y;
    const int b = z >> 1, sel = z & 1;
    const float* x        = (sel ? xs : xq) + (size_t)b * CIN * NHW;
    const _Float16* w     = wf + (size_t)sel * (OD * CIN);
    const float* bias     = sel ? phb : thb;
    _Float16* out         = (sel ? Kws : Qws) + (size_t)b * NHW * OD;
    const int n0 = nt * 64;

    __shared__ __align__(16) char Xs[64 * 128];    // [n][c-chunk 64] f16, swizzled
    __shared__ __align__(16) char Ws[256 * 128];   // [o][c-chunk 64] f16, swizzled

    const int t    = threadIdx.x;
    const int lane = t & 63, wave = t >> 6;
    const int l16  = lane & 15, lh = lane >> 4;

    f32x4 acc[4][4] = {};   // [oo][nn]: rows o = wave*64+oo*16+4lh+r, cols n = nn*16+l16

    for (int c0 = 0; c0 < CIN; c0 += 64) {
        // stage Xs: transpose x[c][n] -> Xs[n][c]
        #pragma unroll
        for (int rep = 0; rep < 4; ++rep) {
            const int ci = rep * 16 + (t >> 4);
            const int nl = (t & 15) * 4;
            const float4 v = *(const float4*)&x[(size_t)(c0 + ci) * NHW + n0 + nl];
            *(_Float16*)(Xs + RSWZ(nl + 0, ci * 2)) = (_Float16)v.x;
            *(_Float16*)(Xs + RSWZ(nl + 1, ci * 2)) = (_Float16)v.y;
            *(_Float16*)(Xs + RSWZ(nl + 2, ci * 2)) = (_Float16)v.z;
            *(_Float16*)(Xs + RSWZ(nl + 3, ci * 2)) = (_Float16)v.w;
        }
        // stage Ws: all 256 o rows, this c-chunk (f16 source)
        #pragma unroll
        for (int r = 0; r < 8; ++r) {
            const int u = r * 256 + t;
            const int o = u >> 3, cs8 = (u & 7) * 8;
            const f16x8 v = *(const f16x8*)(w + (size_t)o * CIN + c0 + cs8);
            *(f16x8*)(Ws + RSWZ(o, cs8 * 2)) = v;
        }
        __syncthreads();

        #pragma unroll
        for (int kk = 0; kk < 2; ++kk) {
            f16x8 af[4];
            #pragma unroll
            for (int oo = 0; oo < 4; ++oo)
                af[oo] = *(const f16x8*)(Ws + RSWZ(wave * 64 + oo * 16 + l16, kk * 64 + lh * 16));
            #pragma unroll
            for (int nn = 0; nn < 4; ++nn) {
                const f16x8 bf = *(const f16x8*)(Xs + RSWZ(nn * 16 + l16, kk * 64 + lh * 16));
                #pragma unroll
                for (int oo = 0; oo < 4; ++oo)
                    acc[oo][nn] = MFMA16(af[oo], bf, acc[oo][nn]);
            }
        }
        __syncthreads();
    }

    // epilogue: lane holds o = wave*64+oo*16+lh*4+r, n = nn*16+l16 -> f16x4 stores
    #pragma unroll
    for (int oo = 0; oo < 4; ++oo) {
        const float4 bi = *(const float4*)&bias[wave * 64 + oo * 16 + lh * 4];
        #pragma unroll
        for (int nn = 0; nn < 4; ++nn) {
            f16x4 v;
            v[0] = (_Float16)(acc[oo][nn][0] + bi.x);
            v[1] = (_Float16)(acc[oo][nn][1] + bi.y);
            v[2] = (_Float16)(acc[oo][nn][2] + bi.z);
            v[3] = (_Float16)(acc[oo][nn][3] + bi.w);
            const int n = n0 + nn * 16 + l16;
            *(f16x4*)&out[(size_t)n * OD + wave * 64 + oo * 16 + lh * 4] = v;
        }
    }
}

// ---------------------------------------------------------------------------
// Compact mask (ordered). idx[b][k] = source n of k-th unmasked pixel (0-pad
// to Npad=ceil64(Nb)); nbArr[b*2]=Nb, nbArr[b*2+1]=Npad/32 (flash tile count).
// ---------------------------------------------------------------------------
__global__ __launch_bounds__(256)
void compact_mask(const float* __restrict__ mask, int* __restrict__ idx,
                  int* __restrict__ nbArr)
{
    const int b = blockIdx.x, t = threadIdx.x;
    const float* mb = mask + (size_t)b * NHW;
    __shared__ int cnt[256];
    __shared__ int pre[257];

    const int base = t * 16;
    float mv[16];
    int c = 0;
    #pragma unroll
    for (int i = 0; i < 16; ++i) { mv[i] = mb[base + i]; c += (mv[i] != 0.0f); }
    cnt[t] = c;
    __syncthreads();
    if (t == 0) {
        int s = 0;
        for (int i = 0; i < 256; ++i) { pre[i] = s; s += cnt[i]; }
        pre[256] = s;
    }
    __syncthreads();
    int o = pre[t];
    #pragma unroll
    for (int i = 0; i < 16; ++i)
        if (mv[i] != 0.0f) idx[(size_t)b * NHW + o++] = base + i;

    const int Nb = pre[256];
    const int Npad = (Nb + 63) & ~63;
    for (int k = Nb + t; k < Npad; k += 256) idx[(size_t)b * NHW + k] = 0;
    if (t == 0) { nbArr[b * 2] = Nb; nbArr[b * 2 + 1] = Npad >> 5; }
}

// ---------------------------------------------------------------------------
// Gather K rows and V columns into compacted, PRE-SWIZZLED f16 buffers.
// Kc_sw: row k, 16B unit c16 stored at byte k*512 + ((c16*16) ^ ((k&7)<<4)).
// Vc_sw: row o, within each 32-k chunk unit uin stored at uin ^ ((o>>1)&3).
// grid (64, 8), block 256.
// ---------------------------------------------------------------------------
__global__ __launch_bounds__(256)
void gather_kv(const _Float16* __restrict__ Kws, const float* __restrict__ emb,
               const int* __restrict__ idx, const int* __restrict__ nbArr,
               _Float16* __restrict__ Kc, _Float16* __restrict__ Vc)
{
    const int b = blockIdx.y, k0 = blockIdx.x * 64, t = threadIdx.x;
    const int Nb = nbArr[b * 2];
    const int Npad = (Nb + 63) & ~63;
    if (k0 >= Npad) return;

    __shared__ int sidx[64];
    if (t < 64) sidx[t] = idx[(size_t)b * NHW + k0 + t];
    __syncthreads();

    const _Float16* Kb = Kws + (size_t)b * NHW * OD;
    char* KcB = (char*)(Kc + (size_t)b * NHW * OD);
    #pragma unroll
    for (int r = 0; r < 8; ++r) {
        const int u = r * 256 + t;               // 64 rows x 32 units
        const int row = u >> 5, c16 = u & 31;
        const f16x8 v = *(const f16x8*)(Kb + (size_t)sidx[row] * OD + c16 * 8);
        *(f16x8*)(KcB + (size_t)(k0 + row) * 512 + ((c16 * 16) ^ ((row & 7) << 4))) = v;
    }

    const float* eb = emb + (size_t)b * OD * NHW;
    char* VcB = (char*)(Vc + (size_t)b * OD * NHW);
    #pragma unroll
    for (int r = 0; r < 8; ++r) {
        const int u = r * 256 + t;               // 256 o x 8 units
        const int o = u >> 3, uc = u & 7;
        const int chunk = uc >> 2, uin = uc & 3;
        float4 a, c;
        #pragma unroll
        for (int i = 0; i < 4; ++i) ((float*)&a)[i] = eb[(size_t)o * NHW + sidx[uc * 8 + i]];
        #pragma unroll
        for (int i = 0; i < 4; ++i) ((float*)&c)[i] = eb[(size_t)o * NHW + sidx[uc * 8 + 4 + i]];
        const f16x8 v = cvt8(a, c);
        *(f16x8*)(VcB + (size_t)o * (NHW * 2) + (size_t)k0 * 2 + chunk * 64
                      + ((uin ^ ((o >> 1) & 3)) * 16)) = v;
    }
}

// ---------------------------------------------------------------------------
// Flash attention, swapped-operand QK^T, per-lane softmax, register P
// re-fragmentation, dbuf K/V LDS, DUAL q-group per wave (each LDS fragment
// read feeds 2 MFMAs -> halved LDS traffic per FLOP).
// QBLK=128 (4 waves x 32 q). grid 256 (b = bid&7 -> one batch per XCD).
// LDS 64 KB, 1 block/CU, VGPR budget relaxed via launch_bounds(256,1).
// ---------------------------------------------------------------------------
__device__ __forceinline__ void load_tile(const char* __restrict__ Kb,
                                          const char* __restrict__ Vb,
                                          int j, int t,
                                          f16x8 (&kst)[4], f16x8 (&vst)[4])
{
    const char* kb = Kb + (size_t)j * (KBLK * 512);
    #pragma unroll
    for (int r = 0; r < 4; ++r)
        kst[r] = *(const f16x8*)(kb + (r * 256 + t) * 16);
    #pragma unroll
    for (int r = 0; r < 4; ++r) {
        const int u = r * 256 + t, o = u >> 2, sl = u & 3;
        vst[r] = *(const f16x8*)(Vb + (size_t)o * (NHW * 2) + (size_t)j * 64 + sl * 16);
    }
}

__global__ __launch_bounds__(256, 1)
void flash_attn(const _Float16* __restrict__ Qws, const _Float16* __restrict__ Kc,
                const _Float16* __restrict__ Vc, const int* __restrict__ nbArr,
                float* __restrict__ outp)
{
    const int bid = blockIdx.x;
    const int b = bid & 7, qt = bid >> 3;
    const int t = threadIdx.x, lane = t & 63, wave = t >> 6;
    const int l16 = lane & 15, lh = lane >> 4;

    __shared__ __align__(16) char Kl[2][KBLK * 512];   // 2 x 16 KB (swizzled)
    __shared__ __align__(16) char Vl[2][OD * 64];      // 2 x 16 KB (swizzled)

    const _Float16* Qb = Qws + (size_t)b * NHW * OD;
    const char* Kb = (const char*)(Kc + (size_t)b * NHW * OD);
    const char* Vb = (const char*)(Vc + (size_t)b * OD * NHW);
    const int Nb = nbArr[b * 2];
    const int nt = nbArr[b * 2 + 1];

    // Q fragments, 2 groups: lane l16 = q-row within group
    f16x8 qf[8][2];
    #pragma unroll
    for (int g = 0; g < 2; ++g) {
        const _Float16* qrow = Qb
            + (size_t)(qt * 128 + wave * 32 + g * 16 + l16) * OD + lh * 8;
        #pragma unroll
        for (int kk = 0; kk < 8; ++kk) qf[kk][g] = *(const f16x8*)(qrow + kk * 32);
    }

    f32x4 accO[16][2] = {};          // D[o][q] per group
    float M0 = -INFINITY, L0 = 0.f;  // per-lane softmax state, group 0
    float M1 = -INFINITY, L1 = 0.f;  // group 1

    f16x8 kst[4], vst[4];
    load_tile(Kb, Vb, 0, t, kst, vst);
    #pragma unroll
    for (int r = 0; r < 4; ++r) {
        *(f16x8*)(Kl[0] + (r * 256 + t) * 16) = kst[r];
        *(f16x8*)(Vl[0] + (r * 256 + t) * 16) = vst[r];
    }
    if (nt > 1) load_tile(Kb, Vb, 1, t, kst, vst);
    __syncthreads();

    #pragma unroll 1
    for (int jt = 0; jt < nt; ++jt) {
        const int cur = jt & 1;
        // ---- stage next tile regs -> other buffer
        if (jt + 1 < nt) {
            #pragma unroll
            for (int r = 0; r < 4; ++r) {
                *(f16x8*)(Kl[cur ^ 1] + (r * 256 + t) * 16) = kst[r];
                *(f16x8*)(Vl[cur ^ 1] + (r * 256 + t) * 16) = vst[r];
            }
        }
        // ---- issue loads for tile jt+2
        if (jt + 2 < nt) load_tile(Kb, Vb, jt + 2, t, kst, vst);

        // ---- S' = K Q^T (swapped): each kf read feeds BOTH q-groups
        f32x4 S[2][2] = {};
        #pragma unroll
        for (int ct = 0; ct < 2; ++ct) {
            const int row = ct * 16 + l16;
            #pragma unroll
            for (int kk = 0; kk < 8; ++kk) {
                const f16x8 kf = *(const f16x8*)(Kl[cur] + row * 512
                                     + ((kk * 64 + lh * 16) ^ ((row & 7) << 4)));
                S[ct][0] = MFMA16(kf, qf[kk][0], S[ct][0]);
                S[ct][1] = MFMA16(kf, qf[kk][1], S[ct][1]);
            }
        }

        // ---- logits (k indices shared across groups)
        const bool tail = (jt * 32 + 32 > Nb);
        float lg[8][2];
        #pragma unroll
        for (int ct = 0; ct < 2; ++ct)
            #pragma unroll
            for (int r = 0; r < 4; ++r) {
                float v0 = S[ct][0][r] * 0.25f;
                float v1 = S[ct][1][r] * 0.25f;
                if (tail) {
                    const int kg = jt * 32 + ct * 16 + lh * 4 + r;
                    if (kg >= Nb) { v0 = -1e30f; v1 = -1e30f; }
                }
                lg[ct * 4 + r][0] = v0;
                lg[ct * 4 + r][1] = v1;
            }

        // ---- per-lane row max (per group)
        float m80 = lg[0][0], m81 = lg[0][1];
        #pragma unroll
        for (int i = 1; i < 8; ++i) { m80 = fmaxf(m80, lg[i][0]); m81 = fmaxf(m81, lg[i][1]); }
        m80 = fmaxf(m80, __shfl_xor(m80, 16));
        m80 = fmaxf(m80, __shfl_xor(m80, 32));
        m81 = fmaxf(m81, __shfl_xor(m81, 16));
        m81 = fmaxf(m81, __shfl_xor(m81, 32));

        // ---- deferred rescale (THR=8), one branch for both groups
        if (__any((m80 > M0 + 8.0f) || (m81 > M1 + 8.0f))) {
            const float nm0 = fmaxf(M0, m80), nm1 = fmaxf(M1, m81);
            const float f0 = __expf(M0 - nm0), f1 = __expf(M1 - nm1);
            M0 = nm0; L0 *= f0; M1 = nm1; L1 *= f1;
            #pragma unroll
            for (int oo = 0; oo < 16; ++oo)
                #pragma unroll
                for (int r = 0; r < 4; ++r) {
                    accO[oo][0][r] *= f0;
                    accO[oo][1][r] *= f1;
                }
        }

        // ---- P = exp(lg - M), row sums (per group)
        float p0[8], p1[8], s0 = 0.f, s1 = 0.f;
        #pragma unroll
        for (int i = 0; i < 8; ++i) {
            p0[i] = __expf(lg[i][0] - M0); s0 += p0[i];
            p1[i] = __expf(lg[i][1] - M1); s1 += p1[i];
        }
        s0 += __shfl_xor(s0, 16); s0 += __shfl_xor(s0, 32); L0 += s0;
        s1 += __shfl_xor(s1, 16); s1 += __shfl_xor(s1, 32); L1 += s1;

        // ---- re-fragment P per group (pull both halves, select by dest lh&2)
        const int src0 = l16 + (((2 * lh) & 3) << 4);
        const int src1 = src0 + 16;
        const bool hi = (lh & 2) != 0;
        f16x8 pf[2];
        #pragma unroll
        for (int g = 0; g < 2; ++g) {
            const float* p = g ? p1 : p0;
            const uint32_t ps0 = pkh2(p[0], p[1]), ps1 = pkh2(p[2], p[3]);
            const uint32_t ps2 = pkh2(p[4], p[5]), ps3 = pkh2(p[6], p[7]);
            const uint32_t a0 = __shfl(ps0, src0), a2 = __shfl(ps2, src0);
            const uint32_t a1 = __shfl(ps1, src0), a3 = __shfl(ps3, src0);
            const uint32_t b0 = __shfl(ps0, src1), b2 = __shfl(ps2, src1);
            const uint32_t b1 = __shfl(ps1, src1), b3 = __shfl(ps3, src1);
            union { uint32_t u[4]; f16x8 v; } pu;
            pu.u[0] = hi ? a2 : a0;
            pu.u[1] = hi ? a3 : a1;
            pu.u[2] = hi ? b2 : b0;
            pu.u[3] = hi ? b3 : b1;
            pf[g] = pu.v;
        }

        // ---- O += V^T P : each vf read feeds BOTH q-groups
        #pragma unroll
        for (int oo = 0; oo < 16; ++oo) {
            const int o = oo * 16 + l16;
            const f16x8 vf = *(const f16x8*)(Vl[cur] + o * 64
                                 + ((lh * 16) ^ (((o >> 1) & 3) << 4)));
            accO[oo][0] = MFMA16(vf, pf[0], accO[oo][0]);
            accO[oo][1] = MFMA16(vf, pf[1], accO[oo][1]);
        }
        __syncthreads();
    }

    // ---- epilogue: lane l16 = q within group; rows o = oo*16+lh*4+r
    const float rl0 = 1.0f / fmaxf(L0, 1e-30f);
    const float rl1 = 1.0f / fmaxf(L1, 1e-30f);
    const int n0 = qt * 128 + wave * 32 + l16;
    #pragma unroll
    for (int oo = 0; oo < 16; ++oo) {
        #pragma unroll
        for (int r = 0; r < 4; ++r) {
            const int o = oo * 16 + lh * 4 + r;
            float* row = outp + ((size_t)b * OD + o) * NHW;
            row[n0]      = accO[oo][0][r] * rl0;
            row[n0 + 16] = accO[oo][1][r] * rl1;
        }
    }
}

extern "C" void kernel_launch(void* const* d_in, const int* in_sizes, int n_in,
                              void* d_out, int out_size, void* d_ws, size_t ws_size,
                              hipStream_t stream) {
    const float* xq   = (const float*)d_in[0];
    const float* xs   = (const float*)d_in[1];
    const float* emb  = (const float*)d_in[2];
    const float* mask = (const float*)d_in[3];
    const float* thw  = (const float*)d_in[4];
    const float* thb  = (const float*)d_in[5];
    const float* phw  = (const float*)d_in[6];
    const float* phb  = (const float*)d_in[7];
    float* out = (float*)d_out;

    const size_t szT = (size_t)BN * NHW * OD;   // elements per f16 tensor
    _Float16* Qws = (_Float16*)d_ws;
    _Float16* Kws = Qws + szT;
    _Float16* Kc  = Kws + szT;
    _Float16* Vc  = Kc + szT;
    _Float16* wf  = Vc + szT;                   // 2*256*512 f16
    int* idxArr   = (int*)(wf + 2 * OD * CIN);
    int* nbArr    = idxArr + (size_t)BN * NHW;

    wcvt<<<dim3(128), 256, 0, stream>>>(thw, phw, wf);
    compact_mask<<<dim3(BN), 256, 0, stream>>>(mask, idxArr, nbArr);
    prep_gemm<<<dim3(64, 16), 256, 0, stream>>>(xq, xs, wf, thb, phb, Qws, Kws);
    gather_kv<<<dim3(64, BN), 256, 0, stream>>>(Kws, emb, idxArr, nbArr, Kc, Vc);
    flash_attn<<<dim3(256), 256, 0, stream>>>(Qws, Kc, Vc, nbArr, out);
}